// Round 2
// baseline (1079.519 us; speedup 1.0000x reference)
//
#include <hip/hip_runtime.h>
#include <math.h>

#define M_TOKENS 32768
#define D_MODEL  4096
#define N_EXPERTS 64

constexpr int BT  = 64;         // tokens per block
constexpr int BK  = 64;         // k-chunk
constexpr int LDW = BK + 4;     // 68 floats: 16B-aligned rows, 2-way-max bank aliasing (free)
constexpr int LDS_S = 65;       // score tile leading dim

__global__ __launch_bounds__(256, 4)
void topk_router_kernel(const float* __restrict__ X,
                        const float* __restrict__ W,
                        const float* __restrict__ b,
                        float* __restrict__ out)
{
    __shared__ float Xs[BT * LDW];        // 17408 B
    __shared__ float Ws[N_EXPERTS * LDW]; // 17408 B

    const int tid = threadIdx.x;
    const int t0  = blockIdx.x * BT;

    const int ti = tid & 15;   // token-group 0..15  -> tokens ti*4..+3
    const int ei = tid >> 4;   // expert-group 0..15 -> experts ei*4..+3

    // high-precision master accumulators (fp64) + per-chunk fp32 accumulators
    double dacc[4][4];
#pragma unroll
    for (int i = 0; i < 4; ++i)
#pragma unroll
        for (int j = 0; j < 4; ++j) dacc[i][j] = 0.0;

    for (int k0 = 0; k0 < D_MODEL; k0 += BK) {
        __syncthreads();   // previous iteration's readers done before overwrite
#pragma unroll
        for (int it = 0; it < 4; ++it) {
            const int f   = tid + it * 256;   // 0..1023
            const int row = f >> 4;           // 0..63
            const int col = (f & 15) << 2;    // 0..60 step 4
            const float4 xv = *reinterpret_cast<const float4*>(
                &X[(size_t)(t0 + row) * D_MODEL + k0 + col]);
            *reinterpret_cast<float4*>(&Xs[row * LDW + col]) = xv;
            const float4 wv = *reinterpret_cast<const float4*>(
                &W[(size_t)row * D_MODEL + k0 + col]);
            *reinterpret_cast<float4*>(&Ws[row * LDW + col]) = wv;
        }
        __syncthreads();

        float cacc[4][4];
#pragma unroll
        for (int i = 0; i < 4; ++i)
#pragma unroll
            for (int j = 0; j < 4; ++j) cacc[i][j] = 0.f;

#pragma unroll
        for (int k4 = 0; k4 < BK / 4; ++k4) {
            float4 xf[4], wf[4];
#pragma unroll
            for (int i = 0; i < 4; ++i)
                xf[i] = *reinterpret_cast<const float4*>(&Xs[(ti * 4 + i) * LDW + k4 * 4]);
#pragma unroll
            for (int j = 0; j < 4; ++j)
                wf[j] = *reinterpret_cast<const float4*>(&Ws[(ei * 4 + j) * LDW + k4 * 4]);
#pragma unroll
            for (int i = 0; i < 4; ++i)
#pragma unroll
                for (int j = 0; j < 4; ++j) {
                    cacc[i][j] = fmaf(xf[i].x, wf[j].x, cacc[i][j]);
                    cacc[i][j] = fmaf(xf[i].y, wf[j].y, cacc[i][j]);
                    cacc[i][j] = fmaf(xf[i].z, wf[j].z, cacc[i][j]);
                    cacc[i][j] = fmaf(xf[i].w, wf[j].w, cacc[i][j]);
                }
        }

        // promote chunk partials into fp64 master (16 cvt + 16 add per 1024 FMAs)
#pragma unroll
        for (int i = 0; i < 4; ++i)
#pragma unroll
            for (int j = 0; j < 4; ++j) dacc[i][j] += (double)cacc[i][j];
    }

    // scores -> LDS (reuse Xs; 64*65 = 4160 <= 64*68 = 4352)
    __syncthreads();
    float* Ss = Xs;
#pragma unroll
    for (int i = 0; i < 4; ++i)
#pragma unroll
        for (int j = 0; j < 4; ++j)
            Ss[(ti * 4 + i) * LDS_S + (ei * 4 + j)] = (float)dacc[i][j];
    __syncthreads();

    // one thread per token: top-2 scan (lowest-index tie-break) + softmax
    if (tid < BT) {
        const int t = tid;
        float best = -INFINITY, second = -INFINITY;
        int bi = 0, si = 0;
        for (int e = 0; e < N_EXPERTS; ++e) {
            const float s = Ss[t * LDS_S + e] + b[e];
            if (s > best) {
                second = best; si = bi;
                best = s;      bi = e;
            } else if (s > second) {
                second = s;    si = e;
            }
        }
        const float e2 = expf(second - best);
        const float inv = 1.0f / (1.0f + e2);

        const size_t tg = (size_t)(t0 + t);
        out[tg * 2 + 0] = inv;
        out[tg * 2 + 1] = e2 * inv;
        float* idx_out = out + (size_t)M_TOKENS * 2;
        idx_out[tg * 2 + 0] = (float)bi;
        idx_out[tg * 2 + 1] = (float)si;
    }
}

extern "C" void kernel_launch(void* const* d_in, const int* in_sizes, int n_in,
                              void* d_out, int out_size, void* d_ws, size_t ws_size,
                              hipStream_t stream) {
    const float* X = (const float*)d_in[0];
    const float* W = (const float*)d_in[1];
    const float* b = (const float*)d_in[2];
    float* out = (float*)d_out;

    dim3 grid(M_TOKENS / BT);   // 512
    dim3 block(256);
    hipLaunchKernelGGL(topk_router_kernel, grid, block, 0, stream, X, W, b, out);
}

// Round 3
// 813.803 us; speedup vs baseline: 1.3265x; 1.3265x over previous
//
#include <hip/hip_runtime.h>
#include <math.h>

typedef short     s16x8 __attribute__((ext_vector_type(8)));
typedef unsigned short u16x4 __attribute__((ext_vector_type(4)));
typedef float     f32x4 __attribute__((ext_vector_type(4)));

#define M_TOKENS 32768
#define D_MODEL  4096
#define N_EXPERTS 64

constexpr int BT   = 64;            // tokens per block
constexpr int BK   = 64;            // k per staging chunk
constexpr int LROW = BK + 8;        // 72 bf16 row stride (144 B) — spreads frag reads over all banks
constexpr int XSPL = BT * LROW;     // per-split X tile size (elements)
constexpr int WSPL = N_EXPERTS * LROW;
constexpr int WSP_STRIDE = N_EXPERTS * D_MODEL;  // 262144 elements per split plane

__device__ __forceinline__ unsigned short f32_to_bf16(float f) {
    unsigned int u = __float_as_uint(f);
    u += 0x7fffu + ((u >> 16) & 1u);           // RNE
    return (unsigned short)(u >> 16);
}
__device__ __forceinline__ float bf16_to_f32(unsigned short h) {
    return __uint_as_float(((unsigned int)h) << 16);
}

// ---- pass 1: split W (64x4096 fp32) into 3 bf16 planes in workspace ----
__global__ void split_w_kernel(const float* __restrict__ W, unsigned short* __restrict__ Wsp) {
    const int idx = blockIdx.x * 256 + threadIdx.x;     // 0 .. 262143
    const float v = W[idx];
    const unsigned short h0 = f32_to_bf16(v);
    const float r1 = v - bf16_to_f32(h0);               // exact (Sterbenz)
    const unsigned short h1 = f32_to_bf16(r1);
    const float r2 = r1 - bf16_to_f32(h1);              // exact
    const unsigned short h2 = f32_to_bf16(r2);
    Wsp[idx]                  = h0;
    Wsp[WSP_STRIDE + idx]     = h1;
    Wsp[2 * WSP_STRIDE + idx] = h2;
}

// ---- pass 2: fused bf16x3 MFMA GEMM + top-2 + softmax ----
// block = 128 threads (2 waves); wave w: tokens w*32..w*32+31 (2 A-tiles) x 64 experts (4 B-tiles)
__global__ __launch_bounds__(128)
void router_mfma_kernel(const float* __restrict__ X,
                        const unsigned short* __restrict__ Wsp,
                        const float* __restrict__ b,
                        float* __restrict__ out)
{
    __shared__ __align__(16) unsigned short Xs[3 * XSPL];  // 27648 B
    __shared__ __align__(16) unsigned short Ws[3 * WSPL];  // 27648 B

    const int tid  = threadIdx.x;
    const int wv   = tid >> 6;
    const int lane = tid & 63;
    const int l15  = lane & 15;
    const int quad = lane >> 4;
    const int t0   = blockIdx.x * BT;

    f32x4 acc[2][4];      // chunk accumulators (fp32 C)
    f32x4 mst[2][4];      // masters (fp32, promoted every 2 chunks)
#pragma unroll
    for (int tt = 0; tt < 2; ++tt)
#pragma unroll
        for (int et = 0; et < 4; ++et) {
            acc[tt][et] = (f32x4){0.f, 0.f, 0.f, 0.f};
            mst[tt][et] = (f32x4){0.f, 0.f, 0.f, 0.f};
        }

    for (int k0 = 0; k0 < D_MODEL; k0 += BK) {
        __syncthreads();   // prior readers done before LDS overwrite

        // ---- stage X: 64 tok x 64 k fp32, split -> 3 bf16 LDS tiles ----
#pragma unroll
        for (int i = 0; i < 8; ++i) {
            const int f   = tid + i * 128;          // 0..1023 float4-granules
            const int row = f >> 4;                 // token 0..63
            const int col = (f & 15) << 2;          // k 0..60
            const float4 xv = *reinterpret_cast<const float4*>(
                &X[(size_t)(t0 + row) * D_MODEL + k0 + col]);
            const float vv[4] = {xv.x, xv.y, xv.z, xv.w};
            u16x4 p0, p1, p2;
#pragma unroll
            for (int c = 0; c < 4; ++c) {
                const unsigned short h0 = f32_to_bf16(vv[c]);
                const float r1 = vv[c] - bf16_to_f32(h0);
                const unsigned short h1 = f32_to_bf16(r1);
                const float r2 = r1 - bf16_to_f32(h1);
                const unsigned short h2 = f32_to_bf16(r2);
                p0[c] = h0; p1[c] = h1; p2[c] = h2;
            }
            const int base = row * LROW + col;
            *reinterpret_cast<u16x4*>(&Xs[0 * XSPL + base]) = p0;
            *reinterpret_cast<u16x4*>(&Xs[1 * XSPL + base]) = p1;
            *reinterpret_cast<u16x4*>(&Xs[2 * XSPL + base]) = p2;
        }

        // ---- stage W (pre-split bf16): 3 x 64 experts x 64 k ----
#pragma unroll
        for (int i = 0; i < 12; ++i) {
            const int g   = tid + i * 128;          // 0..1535 granules of 8 bf16
            const int s   = g >> 9;
            const int rem = g & 511;
            const int e   = rem >> 3;
            const int kq  = (rem & 7) << 3;
            const s16x8 w8 = *reinterpret_cast<const s16x8*>(
                &Wsp[(size_t)s * WSP_STRIDE + e * D_MODEL + k0 + kq]);
            *reinterpret_cast<s16x8*>(&Ws[s * WSPL + e * LROW + kq]) = w8;
        }
        __syncthreads();

        // ---- MFMA inner: 2 ksteps of 32 ----
#pragma unroll
        for (int ks = 0; ks < 2; ++ks) {
            s16x8 af[2][3];
#pragma unroll
            for (int tt = 0; tt < 2; ++tt) {
                const int row  = wv * 32 + tt * 16 + l15;
                const int koff = row * LROW + ks * 32 + quad * 8;
                af[tt][0] = *reinterpret_cast<const s16x8*>(&Xs[0 * XSPL + koff]);
                af[tt][1] = *reinterpret_cast<const s16x8*>(&Xs[1 * XSPL + koff]);
                af[tt][2] = *reinterpret_cast<const s16x8*>(&Xs[2 * XSPL + koff]);
            }
#pragma unroll
            for (int et = 0; et < 4; ++et) {
                const int erow = et * 16 + l15;
                const int koff = erow * LROW + ks * 32 + quad * 8;
                s16x8 bf[3];
                bf[0] = *reinterpret_cast<const s16x8*>(&Ws[0 * WSPL + koff]);
                bf[1] = *reinterpret_cast<const s16x8*>(&Ws[1 * WSPL + koff]);
                bf[2] = *reinterpret_cast<const s16x8*>(&Ws[2 * WSPL + koff]);
#pragma unroll
                for (int tt = 0; tt < 2; ++tt) {
                    f32x4 c = acc[tt][et];
                    c = __builtin_amdgcn_mfma_f32_16x16x32_bf16(af[tt][0], bf[0], c, 0, 0, 0); // hi*hi
                    c = __builtin_amdgcn_mfma_f32_16x16x32_bf16(af[tt][0], bf[1], c, 0, 0, 0); // hi*md
                    c = __builtin_amdgcn_mfma_f32_16x16x32_bf16(af[tt][1], bf[0], c, 0, 0, 0); // md*hi
                    c = __builtin_amdgcn_mfma_f32_16x16x32_bf16(af[tt][1], bf[1], c, 0, 0, 0); // md*md
                    c = __builtin_amdgcn_mfma_f32_16x16x32_bf16(af[tt][0], bf[2], c, 0, 0, 0); // hi*lo
                    c = __builtin_amdgcn_mfma_f32_16x16x32_bf16(af[tt][2], bf[0], c, 0, 0, 0); // lo*hi
                    acc[tt][et] = c;
                }
            }
        }

        // promote chunk (K=128) into masters every 2 k-tiles: keeps acc magnitude small
        if ((k0 >> 6) & 1) {
#pragma unroll
            for (int tt = 0; tt < 2; ++tt)
#pragma unroll
                for (int et = 0; et < 4; ++et) {
#pragma unroll
                    for (int r = 0; r < 4; ++r) mst[tt][et][r] += acc[tt][et][r];
                    acc[tt][et] = (f32x4){0.f, 0.f, 0.f, 0.f};
                }
        }
    }

    // ---- epilogue: scores -> LDS, top-2 + softmax ----
    __syncthreads();
    float* Ss = reinterpret_cast<float*>(Xs);   // 64*65*4 = 16640 B <= 27648
#pragma unroll
    for (int tt = 0; tt < 2; ++tt)
#pragma unroll
        for (int et = 0; et < 4; ++et)
#pragma unroll
            for (int r = 0; r < 4; ++r) {
                const int tok = wv * 32 + tt * 16 + quad * 4 + r;   // C/D: row=(lane>>4)*4+reg
                const int e   = et * 16 + l15;                      //      col=lane&15
                Ss[tok * 65 + e] = mst[tt][et][r];
            }
    __syncthreads();

    if (tid < BT) {
        const int t = tid;
        float best = -INFINITY, second = -INFINITY;
        int bi = 0, si = 0;
        for (int e = 0; e < N_EXPERTS; ++e) {
            const float s = Ss[t * 65 + e] + b[e];
            if (s > best) {
                second = best; si = bi;
                best = s;      bi = e;
            } else if (s > second) {
                second = s;    si = e;
            }
        }
        const float e2 = expf(second - best);
        const float inv = 1.0f / (1.0f + e2);

        const size_t tg = (size_t)(t0 + t);
        out[tg * 2 + 0] = inv;
        out[tg * 2 + 1] = e2 * inv;
        float* idx_out = out + (size_t)M_TOKENS * 2;
        idx_out[tg * 2 + 0] = (float)bi;
        idx_out[tg * 2 + 1] = (float)si;
    }
}

extern "C" void kernel_launch(void* const* d_in, const int* in_sizes, int n_in,
                              void* d_out, int out_size, void* d_ws, size_t ws_size,
                              hipStream_t stream) {
    const float* X = (const float*)d_in[0];
    const float* W = (const float*)d_in[1];
    const float* b = (const float*)d_in[2];
    float* out = (float*)d_out;
    unsigned short* Wsp = (unsigned short*)d_ws;    // needs 3*64*4096*2 = 1.5 MB

    hipLaunchKernelGGL(split_w_kernel, dim3(WSP_STRIDE / 256), dim3(256), 0, stream, W, Wsp);
    hipLaunchKernelGGL(router_mfma_kernel, dim3(M_TOKENS / BT), dim3(128), 0, stream,
                       X, Wsp, b, out);
}